// Round 1
// baseline (4592.860 us; speedup 1.0000x reference)
//
#include <hip/hip_runtime.h>
#include <hip/hip_bf16.h>
#include <math.h>

#define NB 128     // batch (images and captions)
#define NR 36      // regions
#define NW 64      // words
#define ND 1024    // dim
#define ND4 256    // dim in float4
#define EPSF 1e-8f
#define LAM_SM 9.0f
#define LAM_LSE 6.0f
#define MARGINF 0.2f

// ---------- smem layout (floats) for pair kernel ----------
// stage region (reused):
//   imS4  : f4 [0 .. 611]     (36 rows x 17 f4, padded)
//   capS4 : f4 [612 .. 1699]  (64 rows x 17 f4, padded)
//   -> floats 0..6799
// after GEMM1 (overlaps stage region):
//   Mlds : 0..1331      (36 x 37 padded)
//   csP  : 1344..1599   (256 partials)
//   nuP  : 1600..1855
//   qfP  : 1856..2111
// persistent:
//   Araw : 6800..9139   (36 x 65)
//   eS   : 9140..11479  (36 x 65)
//   rnorm: 11480..11515
#define SMF_TOTAL 11516

__device__ __forceinline__ void fma4(float4& acc, const float4 a, const float4 b) {
    acc.x += a.x * b.x; acc.y += a.y * b.y;
    acc.z += a.z * b.z; acc.w += a.w * b.w;
}

// ---------------- kernel A: per-image Gram matrices + caption norms ----------------
__global__ __launch_bounds__(256) void gram_ncap_kernel(
    const float* __restrict__ im, const float* __restrict__ s,
    float* __restrict__ Mg, float* __restrict__ ncap) {
    int b = blockIdx.x;
    int t = threadIdx.x;
    const float4* imb = (const float4*)im + (size_t)b * NR * ND4;
    const float4* sb  = (const float4*)s  + (size_t)b * NW * ND4;
    for (int idx = t; idx < NR * NR + NW; idx += 256) {
        if (idx < NR * NR) {
            int r1 = idx / NR, r2 = idx % NR;
            const float4* p = imb + r1 * ND4;
            const float4* q = imb + r2 * ND4;
            float acc = 0.f;
            for (int k = 0; k < ND4; ++k) {
                float4 a = p[k], c = q[k];
                acc += a.x * c.x + a.y * c.y + a.z * c.z + a.w * c.w;
            }
            Mg[(size_t)b * (NR * NR) + idx] = acc;
        } else {
            int w = idx - NR * NR;
            const float4* p = sb + w * ND4;
            float acc = 0.f;
            for (int k = 0; k < ND4; ++k) {
                float4 a = p[k];
                acc += a.x * a.x + a.y * a.y + a.z * a.z + a.w * a.w;
            }
            ncap[b * NW + w] = sqrtf(acc);
        }
    }
}

// ---------------- kernel B: one block per (image i, caption j) pair ----------------
__global__ __launch_bounds__(256) void pair_scores_kernel(
    const float* __restrict__ im, const float* __restrict__ s,
    const int* __restrict__ s_l, const float* __restrict__ Mg,
    const float* __restrict__ ncap, float* __restrict__ scores) {
    __shared__ __align__(16) float smem[SMF_TOTAL];
    const int i = blockIdx.x;   // image
    const int j = blockIdx.y;   // caption
    const int t = threadIdx.x;
    const int tx = t & 15, ty = t >> 4;
    const int L = s_l[j];

    float4* imS  = (float4*)smem;          // [36][17]
    float4* capS = (float4*)smem + 612;    // [64][17]
    const float4* img4 = (const float4*)im + (size_t)i * NR * ND4;
    const float4* cap4 = (const float4*)s + (size_t)j * NW * ND4;

    // ---- GEMM1: Araw[r][w] = dot(im_i[r], cap_j[w]) ----
    float4 acc[3][4];
    #pragma unroll
    for (int kk = 0; kk < 3; ++kk)
        #pragma unroll
        for (int m = 0; m < 4; ++m)
            acc[kk][m] = make_float4(0.f, 0.f, 0.f, 0.f);

    const bool do3 = (ty < 4);   // wave-uniform: rows ty+32 exist only for ty<4

    for (int ch = 0; ch < 16; ++ch) {
        const int d0 = ch * 16;  // f4 offset within a row
        for (int idx = t; idx < 576; idx += 256) {
            int r = idx >> 4, c = idx & 15;
            imS[r * 17 + c] = img4[r * ND4 + d0 + c];
        }
        for (int idx = t; idx < 1024; idx += 256) {
            int w = idx >> 4, c = idx & 15;
            capS[w * 17 + c] = cap4[w * ND4 + d0 + c];
        }
        __syncthreads();
        for (int dq = 0; dq < 16; ++dq) {
            float4 bv[4];
            #pragma unroll
            for (int m = 0; m < 4; ++m) bv[m] = capS[(tx + 16 * m) * 17 + dq];
            float4 a0 = imS[ty * 17 + dq];
            float4 a1 = imS[(ty + 16) * 17 + dq];
            #pragma unroll
            for (int m = 0; m < 4; ++m) fma4(acc[0][m], a0, bv[m]);
            #pragma unroll
            for (int m = 0; m < 4; ++m) fma4(acc[1][m], a1, bv[m]);
            if (do3) {
                float4 a2 = imS[(ty + 32) * 17 + dq];
                #pragma unroll
                for (int m = 0; m < 4; ++m) fma4(acc[2][m], a2, bv[m]);
            }
        }
        __syncthreads();
    }

    // ---- write Araw to LDS; load Gram into (now free) stage region ----
    float* Araw  = smem + 6800;   // [36][65]
    float* eS    = smem + 9140;   // [36][65]
    float* rnorm = smem + 11480;  // [36]
    float* Mlds  = smem;          // [36][37]
    float* csP   = smem + 1344;
    float* nuP   = smem + 1600;
    float* qfP   = smem + 1856;

    #pragma unroll
    for (int kk = 0; kk < 3; ++kk) {
        if (kk < 2 || do3) {
            int r = ty + 16 * kk;
            #pragma unroll
            for (int m = 0; m < 4; ++m) {
                float4 v = acc[kk][m];
                Araw[r * 65 + tx + 16 * m] = v.x + v.y + v.z + v.w;
            }
        }
    }
    for (int idx = t; idx < NR * NR; idx += 256) {
        Mlds[(idx / NR) * 37 + (idx % NR)] = Mg[(size_t)i * (NR * NR) + idx];
    }
    __syncthreads();

    // ---- per-row l2 norm over masked, leaky words ----
    if (t < 144) {
        int r = t >> 2, q = t & 3;
        float ss = 0.f;
        for (int k = 0; k < 16; ++k) {
            int w = q * 16 + k;
            float v = Araw[r * 65 + w];
            float lv = v > 0.f ? v : 0.1f * v;
            if (w < L) ss += lv * lv;
        }
        ss += __shfl_xor(ss, 1, 64);
        ss += __shfl_xor(ss, 2, 64);
        if (q == 0) rnorm[r] = 1.0f / (sqrtf(ss) + EPSF);
    }
    __syncthreads();

    // ---- e[r][w] = exp(9 * An[r][w]) ----
    for (int idx = t; idx < NR * NW; idx += 256) {
        int r = idx >> 6, w = idx & 63;
        float v = Araw[r * 65 + w];
        float lv = v > 0.f ? v : 0.1f * v;
        float an = (w < L) ? lv * rnorm[r] : 0.f;
        eS[r * 65 + w] = expf(LAM_SM * an);
    }
    __syncthreads();

    // ---- partials: colsum, num (= Σ e*Araw), quadform e^T M e ----
    {
        const int w = t & 63, rs = t >> 6;  // rows rs*9 .. rs*9+8
        float e_my[9];
        float csp = 0.f, nup = 0.f;
        #pragma unroll
        for (int k = 0; k < 9; ++k) {
            int r = rs * 9 + k;
            float ev = eS[r * 65 + w];
            e_my[k] = ev;
            csp += ev;
            nup += ev * Araw[r * 65 + w];
        }
        float y[9];
        #pragma unroll
        for (int k = 0; k < 9; ++k) y[k] = 0.f;
        for (int rp = 0; rp < NR; ++rp) {
            float ev = eS[rp * 65 + w];
            #pragma unroll
            for (int k = 0; k < 9; ++k)
                y[k] += Mlds[(rs * 9 + k) * 37 + rp] * ev;
        }
        float qfp = 0.f;
        #pragma unroll
        for (int k = 0; k < 9; ++k) qfp += y[k] * e_my[k];
        csP[t] = csp; nuP[t] = nup; qfP[t] = qfp;
    }
    __syncthreads();

    // ---- finalize per word, LSE over words, write score ----
    if (t < 64) {
        float cs = csP[t] + csP[64 + t] + csP[128 + t] + csP[192 + t];
        float nu = nuP[t] + nuP[64 + t] + nuP[128 + t] + nuP[192 + t];
        float qf = qfP[t] + qfP[64 + t] + qfP[128 + t] + qfP[192 + t];
        float num  = nu / cs;
        float nwei = sqrtf(fmaxf(qf, 0.f)) / cs;
        float nc   = ncap[j * NW + t];
        float rowv = num / fmaxf(nc * nwei, EPSF);
        float contrib = (t < L) ? expf(LAM_LSE * rowv) : 0.f;
        #pragma unroll
        for (int off = 32; off; off >>= 1) contrib += __shfl_xor(contrib, off, 64);
        if (t == 0) scores[i * NB + j] = logf(contrib) / LAM_LSE;
    }
}

// ---------------- kernel C: contrastive loss reduction ----------------
__global__ __launch_bounds__(128) void loss_kernel(const float* __restrict__ S,
                                                   float* __restrict__ out) {
    __shared__ float part[NB];
    int t = threadIdx.x;
    float dii = S[t * NB + t];
    float rmax = 0.f, cmax = 0.f;
    for (int k = 0; k < NB; ++k) {
        if (k != t) {
            float vs = MARGINF + S[t * NB + k] - dii;   // caption retrieval (row t)
            rmax = fmaxf(rmax, fmaxf(vs, 0.f));
            float vi = MARGINF + S[k * NB + t] - dii;   // image retrieval (col t)
            cmax = fmaxf(cmax, fmaxf(vi, 0.f));
        }
    }
    part[t] = rmax + cmax;
    __syncthreads();
    if (t == 0) {
        float sum = 0.f;
        for (int k = 0; k < NB; ++k) sum += part[k];
        out[0] = sum;
    }
}

extern "C" void kernel_launch(void* const* d_in, const int* in_sizes, int n_in,
                              void* d_out, int out_size, void* d_ws, size_t ws_size,
                              hipStream_t stream) {
    const float* im  = (const float*)d_in[0];
    const float* s   = (const float*)d_in[1];
    const int*   s_l = (const int*)d_in[2];

    float* scores = (float*)d_ws;                       // 128*128
    float* Mg     = scores + NB * NB;                   // 128*36*36
    float* ncap   = Mg + (size_t)NB * NR * NR;          // 128*64

    gram_ncap_kernel<<<NB, 256, 0, stream>>>(im, s, Mg, ncap);
    dim3 grid(NB, NB);
    pair_scores_kernel<<<grid, 256, 0, stream>>>(im, s, s_l, Mg, ncap, scores);
    loss_kernel<<<1, NB, 0, stream>>>(scores, (float*)d_out);
}

// Round 2
// 673.861 us; speedup vs baseline: 6.8157x; 6.8157x over previous
//
#include <hip/hip_runtime.h>
#include <hip/hip_bf16.h>
#include <math.h>
#include <stdint.h>

#define NB 128     // batch (images and captions)
#define NR 36      // regions
#define NW 64      // words
#define ND 1024    // dim
#define ND4 256    // dim in float4
#define MT 48      // NR padded to 3 MFMA m-tiles
#define BK 32      // K per MFMA / per stage chunk
#define EPSF 1e-8f
#define LAM_SM 9.0f
#define LAM_LSE 6.0f
#define MARGINF 0.2f

typedef _Float16 f16;
typedef f16 f16x4 __attribute__((ext_vector_type(4)));
typedef f16 f16x8 __attribute__((ext_vector_type(8)));
typedef float f32x4 __attribute__((ext_vector_type(4)));

// async global->LDS, 16B per lane. LDS dest is wave-uniform base + lane*16;
// we pass per-lane (base + lane*16) which is consistent with either reading.
__device__ __forceinline__ void gld_lds16(const void* g, void* l) {
    __builtin_amdgcn_global_load_lds(
        (const __attribute__((address_space(1))) uint32_t*)(uintptr_t)g,
        (__attribute__((address_space(3))) uint32_t*)(uint32_t)(uintptr_t)l,
        16, 0, 0);
}

// ---------------- kernel 0: fp32 -> f16, im zero-padded to 48 rows ----------------
__global__ __launch_bounds__(256) void convert_kernel(
    const float* __restrict__ im, const float* __restrict__ s,
    f16* __restrict__ im16, f16* __restrict__ s16) {
    const int b = blockIdx.x, row = blockIdx.y, t = threadIdx.x;
    if (row < MT) {
        f16x4* dst = (f16x4*)(im16 + ((size_t)b * MT + row) * ND);
        if (row < NR) {
            const float4* src = (const float4*)(im + ((size_t)b * NR + row) * ND);
            float4 v = src[t];
            f16x4 h = {(f16)v.x, (f16)v.y, (f16)v.z, (f16)v.w};
            dst[t] = h;
        } else {
            f16x4 z = {(f16)0.f, (f16)0.f, (f16)0.f, (f16)0.f};
            dst[t] = z;
        }
    } else {
        const int w = row - MT;
        const float4* src = (const float4*)(s + ((size_t)b * NW + w) * ND);
        float4 v = src[t];
        f16x4 h = {(f16)v.x, (f16)v.y, (f16)v.z, (f16)v.w};
        f16x4* dst = (f16x4*)(s16 + ((size_t)b * NW + w) * ND);
        dst[t] = h;
    }
}

// ---------------- kernel A: per-image Gram matrices + caption norms ----------------
__global__ __launch_bounds__(256) void gram_ncap_kernel(
    const float* __restrict__ im, const float* __restrict__ s,
    float* __restrict__ Mg, float* __restrict__ ncap) {
    int b = blockIdx.x;
    int t = threadIdx.x;
    const float4* imb = (const float4*)im + (size_t)b * NR * ND4;
    const float4* sb  = (const float4*)s  + (size_t)b * NW * ND4;
    for (int idx = t; idx < NR * NR + NW; idx += 256) {
        if (idx < NR * NR) {
            int r1 = idx / NR, r2 = idx % NR;
            const float4* p = imb + r1 * ND4;
            const float4* q = imb + r2 * ND4;
            float acc = 0.f;
            for (int k = 0; k < ND4; ++k) {
                float4 a = p[k], c = q[k];
                acc += a.x * c.x + a.y * c.y + a.z * c.z + a.w * c.w;
            }
            Mg[(size_t)b * (NR * NR) + idx] = acc;
        } else {
            int w = idx - NR * NR;
            const float4* p = sb + w * ND4;
            float acc = 0.f;
            for (int k = 0; k < ND4; ++k) {
                float4 a = p[k];
                acc += a.x * a.x + a.y * a.y + a.z * a.z + a.w * a.w;
            }
            ncap[b * NW + w] = sqrtf(acc);
        }
    }
}

// ---------------- kernel B: one block per (image i, caption j) pair, MFMA ----------
// smem float layout:
//   stage  [0 .. 1792)      A_lds f16[48][32] (3KB) + B_lds f16[64][32] (4KB)
//   Araw   [1792 .. 4132)   f32 [36][65]
//   eS     [4132 .. 6472)   f32 [36][65]
//   rnorm  [6472 .. 6508)
//   Mlds   [0 .. 1332)      f32 [36][37]  (overlays dead stage region post-GEMM)
//   csP/nuP/qfP [6508 .. 7276)
#define A_BYTES (MT * BK * 2)          // 3072
#define STAGE_F 1792
#define SMF_TOTAL 7276

__global__ __launch_bounds__(256) void pair_mfma_kernel(
    const f16* __restrict__ im16, const f16* __restrict__ s16,
    const int* __restrict__ s_l, const float* __restrict__ Mg,
    const float* __restrict__ ncap, float* __restrict__ scores) {
    __shared__ __align__(16) float smem[SMF_TOTAL];
    const int i = blockIdx.x;   // image
    const int j = blockIdx.y;   // caption
    const int t = threadIdx.x;
    const int wave = t >> 6, lane = t & 63;
    const int quad = lane >> 4, l16 = lane & 15;
    const int L = s_l[j];

    char* smemb = (char*)smem;
    const f16* Abase = im16 + (size_t)i * (MT * ND);
    const f16* Bbase = s16  + (size_t)j * (NW * ND);

    f32x4 acc[3];
    acc[0] = (f32x4){0.f, 0.f, 0.f, 0.f};
    acc[1] = (f32x4){0.f, 0.f, 0.f, 0.f};
    acc[2] = (f32x4){0.f, 0.f, 0.f, 0.f};

    for (int kk = 0; kk < ND; kk += BK) {
        // ---- stage A (3KB) + B (4KB): 7 wave-issues of 1KB each ----
        for (int q = wave; q < 7; q += 4) {
            const int F = q * 1024 + lane * 16;
            const f16* src;
            if (F < A_BYTES) {
                int row = F >> 6, ko = (F & 63) >> 1;
                src = Abase + row * ND + kk + ko;
            } else {
                int F2 = F - A_BYTES;
                int row = F2 >> 6, ko = (F2 & 63) >> 1;
                src = Bbase + row * ND + kk + ko;
            }
            gld_lds16(src, smemb + F);
        }
        __syncthreads();
        // ---- fragments + MFMA: wave w owns n-tile w, all 3 m-tiles ----
        f16x8 bf = *(const f16x8*)(smemb + A_BYTES + (wave * 16 + l16) * (BK * 2) + quad * 16);
        #pragma unroll
        for (int mi = 0; mi < 3; ++mi) {
            f16x8 af = *(const f16x8*)(smemb + (mi * 16 + l16) * (BK * 2) + quad * 16);
            acc[mi] = __builtin_amdgcn_mfma_f32_16x16x32_f16(af, bf, acc[mi], 0, 0, 0);
        }
        __syncthreads();
    }

    float* Araw  = smem + STAGE_F;    // [36][65]
    float* eS    = Araw + 2340;       // [36][65]
    float* rnorm = eS + 2340;         // [36]
    float* Mlds  = smem;              // [36][37]
    float* csP   = smem + 6508;
    float* nuP   = smem + 6764;
    float* qfP   = smem + 7020;

    // ---- accumulators -> Araw (C-layout: col=lane&15, row=quad*4+reg) ----
    #pragma unroll
    for (int mi = 0; mi < 3; ++mi) {
        #pragma unroll
        for (int r = 0; r < 4; ++r) {
            int row = mi * 16 + quad * 4 + r;
            int col = wave * 16 + l16;
            if (row < NR) Araw[row * 65 + col] = acc[mi][r];
        }
    }
    for (int idx = t; idx < NR * NR; idx += 256)
        Mlds[(idx / NR) * 37 + (idx % NR)] = Mg[(size_t)i * (NR * NR) + idx];
    __syncthreads();

    // ---- per-row l2 norm over masked, leaky words ----
    if (t < 144) {
        int r = t >> 2, q = t & 3;
        float ss = 0.f;
        for (int k = 0; k < 16; ++k) {
            int w = q * 16 + k;
            float v = Araw[r * 65 + w];
            float lv = v > 0.f ? v : 0.1f * v;
            if (w < L) ss += lv * lv;
        }
        ss += __shfl_xor(ss, 1, 64);
        ss += __shfl_xor(ss, 2, 64);
        if (q == 0) rnorm[r] = 1.0f / (sqrtf(ss) + EPSF);
    }
    __syncthreads();

    // ---- e[r][w] = exp(9 * An[r][w]) ----
    for (int idx = t; idx < NR * NW; idx += 256) {
        int r = idx >> 6, w = idx & 63;
        float v = Araw[r * 65 + w];
        float lv = v > 0.f ? v : 0.1f * v;
        float an = (w < L) ? lv * rnorm[r] : 0.f;
        eS[r * 65 + w] = expf(LAM_SM * an);
    }
    __syncthreads();

    // ---- partials: colsum, num (= sum e*Araw), quadform e^T M e ----
    {
        const int w = t & 63, rs = t >> 6;  // rows rs*9 .. rs*9+8
        float e_my[9];
        float csp = 0.f, nup = 0.f;
        #pragma unroll
        for (int k = 0; k < 9; ++k) {
            int r = rs * 9 + k;
            float ev = eS[r * 65 + w];
            e_my[k] = ev;
            csp += ev;
            nup += ev * Araw[r * 65 + w];
        }
        float y[9];
        #pragma unroll
        for (int k = 0; k < 9; ++k) y[k] = 0.f;
        for (int rp = 0; rp < NR; ++rp) {
            float ev = eS[rp * 65 + w];
            #pragma unroll
            for (int k = 0; k < 9; ++k)
                y[k] += Mlds[(rs * 9 + k) * 37 + rp] * ev;
        }
        float qfp = 0.f;
        #pragma unroll
        for (int k = 0; k < 9; ++k) qfp += y[k] * e_my[k];
        csP[t] = csp; nuP[t] = nup; qfP[t] = qfp;
    }
    __syncthreads();

    // ---- finalize per word, LSE over words, write score ----
    if (t < 64) {
        float cs = csP[t] + csP[64 + t] + csP[128 + t] + csP[192 + t];
        float nu = nuP[t] + nuP[64 + t] + nuP[128 + t] + nuP[192 + t];
        float qf = qfP[t] + qfP[64 + t] + qfP[128 + t] + qfP[192 + t];
        float num  = nu / cs;
        float nwei = sqrtf(fmaxf(qf, 0.f)) / cs;
        float nc   = ncap[j * NW + t];
        float rowv = num / fmaxf(nc * nwei, EPSF);
        float contrib = (t < L) ? expf(LAM_LSE * rowv) : 0.f;
        #pragma unroll
        for (int off = 32; off; off >>= 1) contrib += __shfl_xor(contrib, off, 64);
        if (t == 0) scores[i * NB + j] = logf(contrib) / LAM_LSE;
    }
}

// ---------------- kernel C: contrastive loss reduction ----------------
__global__ __launch_bounds__(128) void loss_kernel(const float* __restrict__ S,
                                                   float* __restrict__ out) {
    __shared__ float part[NB];
    int t = threadIdx.x;
    float dii = S[t * NB + t];
    float rmax = 0.f, cmax = 0.f;
    for (int k = 0; k < NB; ++k) {
        if (k != t) {
            float vs = MARGINF + S[t * NB + k] - dii;   // caption retrieval (row t)
            rmax = fmaxf(rmax, fmaxf(vs, 0.f));
            float vi = MARGINF + S[k * NB + t] - dii;   // image retrieval (col t)
            cmax = fmaxf(cmax, fmaxf(vi, 0.f));
        }
    }
    part[t] = rmax + cmax;
    __syncthreads();
    if (t == 0) {
        float sum = 0.f;
        for (int k = 0; k < NB; ++k) sum += part[k];
        out[0] = sum;
    }
}

extern "C" void kernel_launch(void* const* d_in, const int* in_sizes, int n_in,
                              void* d_out, int out_size, void* d_ws, size_t ws_size,
                              hipStream_t stream) {
    const float* im  = (const float*)d_in[0];
    const float* s   = (const float*)d_in[1];
    const int*   s_l = (const int*)d_in[2];

    float* scores = (float*)d_ws;                         // 128*128
    float* Mg     = scores + NB * NB;                     // 128*36*36
    float* ncap   = Mg + (size_t)NB * NR * NR;            // 128*64
    f16*   im16   = (f16*)(ncap + NB * NW);               // 128*48*1024 f16
    f16*   s16    = im16 + (size_t)NB * MT * ND;          // 128*64*1024 f16

    dim3 cgrid(NB, MT + NW);
    convert_kernel<<<cgrid, 256, 0, stream>>>(im, s, im16, s16);
    gram_ncap_kernel<<<NB, 256, 0, stream>>>(im, s, Mg, ncap);
    dim3 grid(NB, NB);
    pair_mfma_kernel<<<grid, 256, 0, stream>>>(im16, s16, s_l, Mg, ncap, scores);
    loss_kernel<<<1, NB, 0, stream>>>(scores, (float*)d_out);
}

// Round 3
// 444.462 us; speedup vs baseline: 10.3335x; 1.5161x over previous
//
#include <hip/hip_runtime.h>
#include <hip/hip_bf16.h>
#include <math.h>
#include <stdint.h>

#define NB 128     // batch (images and captions)
#define NR 36      // regions
#define NW 64      // words
#define ND 1024    // dim
#define ND4 256    // dim in float4
#define MT 48      // NR padded to 3 MFMA m-tiles
#define BK 32      // K per MFMA / per stage chunk
#define EPSF 1e-8f
#define LAM_SM 9.0f
#define LAM_LSE 6.0f
#define MARGINF 0.2f

typedef _Float16 f16;
typedef f16 f16x4 __attribute__((ext_vector_type(4)));
typedef f16 f16x8 __attribute__((ext_vector_type(8)));
typedef float f32x4 __attribute__((ext_vector_type(4)));

__device__ __forceinline__ void gld_lds16(const void* g, void* l) {
    __builtin_amdgcn_global_load_lds(
        (const __attribute__((address_space(1))) uint32_t*)(uintptr_t)g,
        (__attribute__((address_space(3))) uint32_t*)(uint32_t)(uintptr_t)l,
        16, 0, 0);
}

// ---------------- kernel 0: fp32 -> f16, im zero-padded to 48 rows ----------------
__global__ __launch_bounds__(256) void convert_kernel(
    const float* __restrict__ im, const float* __restrict__ s,
    f16* __restrict__ im16, f16* __restrict__ s16) {
    const int b = blockIdx.x, row = blockIdx.y, t = threadIdx.x;
    if (row < MT) {
        f16x4* dst = (f16x4*)(im16 + ((size_t)b * MT + row) * ND);
        if (row < NR) {
            const float4* src = (const float4*)(im + ((size_t)b * NR + row) * ND);
            float4 v = src[t];
            f16x4 h = {(f16)v.x, (f16)v.y, (f16)v.z, (f16)v.w};
            dst[t] = h;
        } else {
            f16x4 z = {(f16)0.f, (f16)0.f, (f16)0.f, (f16)0.f};
            dst[t] = z;
        }
    } else {
        const int w = row - MT;
        const float4* src = (const float4*)(s + ((size_t)b * NW + w) * ND);
        float4 v = src[t];
        f16x4 h = {(f16)v.x, (f16)v.y, (f16)v.z, (f16)v.w};
        f16x4* dst = (f16x4*)(s16 + ((size_t)b * NW + w) * ND);
        dst[t] = h;
    }
}

// ---------------- kernel A: per-image f16 Gram [48][64] (zero-padded) + ncap ------
__global__ __launch_bounds__(256) void gram16_kernel(
    const float* __restrict__ im, const float* __restrict__ s,
    f16* __restrict__ Mg16, float* __restrict__ ncap) {
    const int b = blockIdx.x, part = blockIdx.y;  // part 0..6
    const int wave = threadIdx.x >> 6, lane = threadIdx.x & 63;
    if (part < 6) {
        const float4* imb = (const float4*)im + (size_t)b * NR * ND4;
        for (int c = 0; c < 128; ++c) {
            int cell = (part * 4 + wave) * 128 + c;   // 0..3071
            int r1 = cell >> 6, r2 = cell & 63;
            float v = 0.f;
            if (r1 < NR && r2 < NR) {
                const float4* p = imb + r1 * ND4;
                const float4* q = imb + r2 * ND4;
                float acc = 0.f;
                #pragma unroll
                for (int k = 0; k < 4; ++k) {
                    float4 a = p[k * 64 + lane], d = q[k * 64 + lane];
                    acc += a.x * d.x + a.y * d.y + a.z * d.z + a.w * d.w;
                }
                #pragma unroll
                for (int off = 1; off < 64; off <<= 1) acc += __shfl_xor(acc, off, 64);
                v = acc;
            }
            if (lane == 0) Mg16[(size_t)b * (MT * NW) + cell] = (f16)v;
        }
    } else {
        for (int n = 0; n < 16; ++n) {
            int w = wave * 16 + n;
            const float4* p = (const float4*)s + (size_t)b * NW * ND4 + w * ND4;
            float acc = 0.f;
            #pragma unroll
            for (int k = 0; k < 4; ++k) {
                float4 a = p[k * 64 + lane];
                acc += a.x * a.x + a.y * a.y + a.z * a.z + a.w * a.w;
            }
            #pragma unroll
            for (int off = 1; off < 64; off <<= 1) acc += __shfl_xor(acc, off, 64);
            if (lane == 0) ncap[b * NW + w] = sqrtf(acc);
        }
    }
}

// ---------------- kernel B: one block per (image i, caption j) pair ---------------
// LDS floats:
//   [0..2048)    stage A f16[48][32]+B f16[64][32] (7168B), later eT16 f16 64x[128B] (8192B)
//   [2048..4388) Araw f32 [36][65]
//   [4388..4436) rnorm[48]
//   [4436..4500) contribS[64]
#define A_BYTES (MT * BK * 2)          // 3072
#define SMF_TOTAL 4500

__global__ __launch_bounds__(256) void pair_mfma_kernel(
    const f16* __restrict__ im16, const f16* __restrict__ s16,
    const int* __restrict__ s_l, const f16* __restrict__ Mg16,
    const float* __restrict__ ncap, float* __restrict__ scores) {
    __shared__ __align__(16) float smem[SMF_TOTAL];
    const int i = blockIdx.x;   // image
    const int j = blockIdx.y;   // caption
    const int t = threadIdx.x;
    const int wave = t >> 6, lane = t & 63;
    const int quad = lane >> 4, l16 = lane & 15;
    const int col = wave * 16 + l16;     // this thread's word/column
    const int L = s_l[j];

    char* smemb = (char*)smem;
    const f16* Abase = im16 + (size_t)i * (MT * ND);
    const f16* Bbase = s16  + (size_t)j * (NW * ND);

    // ---- precompute swizzled staging sources (XOR chunk swizzle, 2-way max) ----
    const f16* src0; const f16* src1 = nullptr;
    char *ld0, *ld1 = nullptr;
    {
        int q0 = wave;
        int F = q0 * 1024 + lane * 16;
        int row = (F < A_BYTES) ? (F >> 6) : ((F - A_BYTES) >> 6);
        int pc  = (F < A_BYTES) ? ((F >> 4) & 3) : (((F - A_BYTES) >> 4) & 3);
        int c   = pc ^ (row & 3) ^ ((row >> 2) & 3);
        src0 = ((F < A_BYTES) ? Abase : Bbase) + row * ND + c * 8;
        ld0  = smemb + F;
        if (wave < 3) {
            int F2 = (wave + 4) * 1024 + lane * 16;
            int F2r = F2 - A_BYTES;                    // always B region
            int row2 = F2r >> 6, pc2 = (F2r >> 4) & 3;
            int c2 = pc2 ^ (row2 & 3) ^ ((row2 >> 2) & 3);
            src1 = Bbase + row2 * ND + c2 * 8;
            ld1  = smemb + F2;
        }
    }
    // ---- fragment pointers (loop-invariant) ----
    const int pcf = quad ^ (l16 & 3) ^ ((l16 >> 2) & 3);
    const char* afp0 = smemb + (0 * 16 + l16) * 64 + pcf * 16;
    const char* afp1 = smemb + (1 * 16 + l16) * 64 + pcf * 16;
    const char* afp2 = smemb + (2 * 16 + l16) * 64 + pcf * 16;
    const char* bfp  = smemb + A_BYTES + (wave * 16 + l16) * 64 + pcf * 16;

    f32x4 acc[3];
    acc[0] = (f32x4){0.f, 0.f, 0.f, 0.f};
    acc[1] = (f32x4){0.f, 0.f, 0.f, 0.f};
    acc[2] = (f32x4){0.f, 0.f, 0.f, 0.f};

    for (int kk = 0; kk < ND; kk += BK) {
        gld_lds16(src0 + kk, ld0);
        if (src1) gld_lds16(src1 + kk, ld1);
        __syncthreads();
        f16x8 bf = *(const f16x8*)bfp;
        f16x8 a0 = *(const f16x8*)afp0;
        f16x8 a1 = *(const f16x8*)afp1;
        f16x8 a2 = *(const f16x8*)afp2;
        acc[0] = __builtin_amdgcn_mfma_f32_16x16x32_f16(a0, bf, acc[0], 0, 0, 0);
        acc[1] = __builtin_amdgcn_mfma_f32_16x16x32_f16(a1, bf, acc[1], 0, 0, 0);
        acc[2] = __builtin_amdgcn_mfma_f32_16x16x32_f16(a2, bf, acc[2], 0, 0, 0);
        __syncthreads();
    }

    f16*   eT16     = (f16*)smem;        // 64 rows x 128B, XOR-swizzled chunks
    float* Araw     = smem + 2048;       // [36][65]
    float* rnorm    = smem + 4388;       // [48]
    float* contribS = smem + 4436;       // [64]

    // ---- accumulators -> Araw (C-layout: col=l16(+16*wave), row=quad*4+reg) ----
    #pragma unroll
    for (int mi = 0; mi < 3; ++mi) {
        #pragma unroll
        for (int r = 0; r < 4; ++r) {
            int row = mi * 16 + quad * 4 + r;
            if (row < NR) Araw[row * 65 + col] = acc[mi][r];
        }
    }
    __syncthreads();

    // ---- per-row l2 norm over masked, leaky words (rows 36..47 -> 0) ----
    if (t < 144) {
        int r = t >> 2, q = t & 3;
        float ss = 0.f;
        for (int k = 0; k < 16; ++k) {
            int w = q * 16 + k;
            float v = Araw[r * 65 + w];
            float lv = v > 0.f ? v : 0.1f * v;
            if (w < L) ss += lv * lv;
        }
        ss += __shfl_xor(ss, 1, 64);
        ss += __shfl_xor(ss, 2, 64);
        if (q == 0) rnorm[r] = 1.0f / (sqrtf(ss) + EPSF);
    } else if (t < 156) {
        rnorm[t - 108] = 0.f;   // rnorm[36..47] = 0 (NaN guard for pad rows)
    }
    __syncthreads();

    // ---- e = exp(9*An) from registers; write E^T f16 (swizzled); colsum partials --
    float csp = 0.f, nup = 0.f;
    #pragma unroll
    for (int mi = 0; mi < 3; ++mi) {
        f16x4 ew;
        #pragma unroll
        for (int r = 0; r < 4; ++r) {
            int row = mi * 16 + quad * 4 + r;
            float v = acc[mi][r];
            float lv = v > 0.f ? v : 0.1f * v;
            float an = (col < L) ? lv * rnorm[row] : 0.f;
            float e = expf(LAM_SM * an);
            if (row < NR) { csp += e; nup += e * v; }
            ew[r] = (f16)e;
        }
        int c = mi * 2 + (quad >> 1);
        char* p = (char*)eT16 + col * 128 + ((c ^ (col & 7)) * 16) + (quad & 1) * 8;
        *(f16x4*)p = ew;
    }
    {   // zero rows 48..63 (read by quadform MFMA k-range, M16 there is 0)
        int wz = lane, row0 = 48 + wave * 4;
        int c = row0 >> 3, sub = (row0 >> 2) & 1;
        char* p = (char*)eT16 + wz * 128 + ((c ^ (wz & 7)) * 16) + sub * 8;
        *(f16x4*)p = (f16x4){(f16)0.f, (f16)0.f, (f16)0.f, (f16)0.f};
    }
    csp += __shfl_xor(csp, 16, 64); csp += __shfl_xor(csp, 32, 64);
    nup += __shfl_xor(nup, 16, 64); nup += __shfl_xor(nup, 32, 64);
    __syncthreads();

    // ---- quadform via MFMA: Y = M16 (global, L2) x E^T (LDS) ----
    const f16* Mi = Mg16 + (size_t)i * (MT * NW);
    f32x4 y[3];
    y[0] = (f32x4){0.f, 0.f, 0.f, 0.f};
    y[1] = (f32x4){0.f, 0.f, 0.f, 0.f};
    y[2] = (f32x4){0.f, 0.f, 0.f, 0.f};
    #pragma unroll
    for (int ks = 0; ks < 2; ++ks) {
        int pch = (ks * 4 + quad) ^ (col & 7);
        f16x8 bf = *(const f16x8*)((char*)eT16 + col * 128 + pch * 16);
        #pragma unroll
        for (int mi = 0; mi < 3; ++mi) {
            f16x8 af = *(const f16x8*)(Mi + (mi * 16 + l16) * 64 + ks * 32 + quad * 8);
            y[mi] = __builtin_amdgcn_mfma_f32_16x16x32_f16(af, bf, y[mi], 0, 0, 0);
        }
    }
    float qfp = 0.f;
    #pragma unroll
    for (int mi = 0; mi < 3; ++mi) {
        int row0 = mi * 16 + quad * 4;
        int c = row0 >> 3, sub = (row0 >> 2) & 1;
        f16x4 ev = *(const f16x4*)((char*)eT16 + col * 128 + ((c ^ (col & 7)) * 16) + sub * 8);
        #pragma unroll
        for (int r = 0; r < 4; ++r) qfp += y[mi][r] * (float)ev[r];
    }
    qfp += __shfl_xor(qfp, 16, 64); qfp += __shfl_xor(qfp, 32, 64);

    if (quad == 0) {
        float num  = nup / csp;
        float nwei = sqrtf(fmaxf(qfp, 0.f)) / csp;
        float nc   = ncap[j * NW + col];
        float rowv = num / fmaxf(nc * nwei, EPSF);
        contribS[col] = (col < L) ? expf(LAM_LSE * rowv) : 0.f;
    }
    __syncthreads();

    if (t < 64) {
        float contrib = contribS[t];
        #pragma unroll
        for (int off = 32; off; off >>= 1) contrib += __shfl_xor(contrib, off, 64);
        if (t == 0) scores[i * NB + j] = logf(contrib) / LAM_LSE;
    }
}

// ---------------- kernel C: contrastive loss reduction ----------------
__global__ __launch_bounds__(128) void loss_kernel(const float* __restrict__ S,
                                                   float* __restrict__ out) {
    __shared__ float part[NB];
    int t = threadIdx.x;
    float dii = S[t * NB + t];
    float rmax = 0.f, cmax = 0.f;
    for (int k = 0; k < NB; ++k) {
        if (k != t) {
            float vs = MARGINF + S[t * NB + k] - dii;
            rmax = fmaxf(rmax, fmaxf(vs, 0.f));
            float vi = MARGINF + S[k * NB + t] - dii;
            cmax = fmaxf(cmax, fmaxf(vi, 0.f));
        }
    }
    part[t] = rmax + cmax;
    __syncthreads();
    if (t == 0) {
        float sum = 0.f;
        for (int k = 0; k < NB; ++k) sum += part[k];
        out[0] = sum;
    }
}

extern "C" void kernel_launch(void* const* d_in, const int* in_sizes, int n_in,
                              void* d_out, int out_size, void* d_ws, size_t ws_size,
                              hipStream_t stream) {
    const float* im  = (const float*)d_in[0];
    const float* s   = (const float*)d_in[1];
    const int*   s_l = (const int*)d_in[2];

    float* scores = (float*)d_ws;                          // 16384 f
    float* ncap   = scores + NB * NB;                      // 8192 f
    f16*   Mg16   = (f16*)(ncap + NB * NW);                // 128*48*64 f16
    f16*   im16   = Mg16 + (size_t)NB * MT * NW;           // 128*48*1024 f16
    f16*   s16    = im16 + (size_t)NB * MT * ND;           // 128*64*1024 f16

    dim3 cgrid(NB, MT + NW);
    convert_kernel<<<cgrid, 256, 0, stream>>>(im, s, im16, s16);
    dim3 ggrid(NB, 7);
    gram16_kernel<<<ggrid, 256, 0, stream>>>(im, s, Mg16, ncap);
    dim3 grid(NB, NB);
    pair_mfma_kernel<<<grid, 256, 0, stream>>>(im16, s16, s_l, Mg16, ncap, scores);
    loss_kernel<<<1, NB, 0, stream>>>(scores, (float*)d_out);
}